// Round 4
// baseline (300.322 us; speedup 1.0000x reference)
//
#include <hip/hip_runtime.h>
#include <stdint.h>
#include <stddef.h>

typedef unsigned short u16;
typedef unsigned int u32;
typedef __bf16 bf16x8 __attribute__((ext_vector_type(8)));
typedef __bf16 bf16x4 __attribute__((ext_vector_type(4)));
typedef short s16x4 __attribute__((ext_vector_type(4)));
typedef float f32x4 __attribute__((ext_vector_type(4)));

#define BB  4
#define SS  2048
#define HIDD 1024
#define NH  16
#define DHD 64

// async global->LDS, 16B per lane. LDS dest = wave-uniform base + lane*16.
#define GLD16(gaddr, laddr) \
  __builtin_amdgcn_global_load_lds( \
      (const __attribute__((address_space(1))) u32*)(gaddr), \
      (__attribute__((address_space(3))) u32*)(laddr), 16, 0, 0)

// barrier that waits ONLY on LDS ops (no vmcnt drain — keeps prefetch in flight)
#define LDS_BARRIER() asm volatile("s_waitcnt lgkmcnt(0)\n\ts_barrier" ::: "memory")

// counted-vmcnt barrier: wait until only N vmem ops outstanding, then barrier.
// (T4: never drain to 0 in the main loop — 16 KB of staging stays in flight.)
#define VMB(n) asm volatile("s_waitcnt vmcnt(" #n ")\n\ts_barrier" ::: "memory")

// 2^x. Q is pre-scaled by 0.125*log2(e), so exp(s/8) == EXP2(s').
#if __has_builtin(__builtin_amdgcn_exp2f)
  #define EXP2(x) __builtin_amdgcn_exp2f(x)
#else
  #define EXP2(x) __expf((x) * 0.6931471805599453f)
#endif

__device__ __forceinline__ u16 f2b(float f){
  union { float f; unsigned u; } c; c.f = f;
  unsigned r = c.u + 0x7fffu + ((c.u >> 16) & 1u);
  return (u16)(r >> 16);
}
__device__ __forceinline__ f32x4 mfma32(bf16x8 a, bf16x8 b, f32x4 c){
  return __builtin_amdgcn_mfma_f32_16x16x32_bf16(a, b, c, 0, 0, 0);
}
__device__ __forceinline__ f32x4 mfma16(s16x4 a, s16x4 b, f32x4 c){
  return __builtin_amdgcn_mfma_f32_16x16x16bf16_1k(a, b, c, 0, 0, 0);
}

// ---------------- fused prologue: cvt + all weight transposes ---------------
// blocks: [0,8192) x->bf16 cvt; [8192,11264) Wq/Wk/Wv transpose;
// [11264,11328) fc1_w transpose (lands at wqkv rows 3072..3135);
// [11328,11392) fc2_w transpose; [11392,11424) zero-pad wqkv rows 3136..3199.
__global__ __launch_bounds__(256)
void prep(const float* __restrict__ x, u16* __restrict__ xb,
          const float* __restrict__ Wq, const float* __restrict__ Wk,
          const float* __restrict__ Wv, const float* __restrict__ f1w,
          const float* __restrict__ f2w,
          u16* __restrict__ wqkv, u16* __restrict__ wtf1, u16* __restrict__ wtf2)
{
  __shared__ float tile[32][33];
  int blk = blockIdx.x;
  const int tid = threadIdx.x;
  if (blk < 8192) {
    int i = blk * 1024 + tid * 4;
    float4 v = *reinterpret_cast<const float4*>(&x[i]);
    ushort4 o;
    o.x = f2b(v.x); o.y = f2b(v.y); o.z = f2b(v.z); o.w = f2b(v.w);
    *reinterpret_cast<ushort4*>(&xb[i]) = o;
    return;
  }
  blk -= 8192;
  if (blk >= 3200) {                       // zero-pad rows 3136..3199 of wqkv
    u16* pad = wqkv + (size_t)3136 * 1024;
    uint4 z = make_uint4(0u, 0u, 0u, 0u);
    *reinterpret_cast<uint4*>(&pad[(size_t)(blk - 3200) * 2048 + tid * 8]) = z;
    return;
  }
  const float* in; u16* out; int R, C, c0, r0;
  if (blk < 3072) {
    int m = blk >> 10, t = blk & 1023;
    in = (m == 0) ? Wq : (m == 1) ? Wk : Wv;
    out = wqkv + (size_t)m * 1024 * 1024;
    R = 1024; C = 1024; c0 = (t & 31) * 32; r0 = (t >> 5) * 32;
  } else if (blk < 3136) {
    int t = blk - 3072;
    in = f1w; out = wtf1; R = 1024; C = 64;
    c0 = (t & 1) * 32; r0 = (t >> 1) * 32;
  } else {
    int t = blk - 3136;
    in = f2w; out = wtf2; R = 64; C = 1024;
    c0 = (t & 31) * 32; r0 = (t >> 5) * 32;
  }
  int tx = tid & 31, ty = tid >> 5;
  #pragma unroll
  for (int j = 0; j < 32; j += 8)
    tile[ty + j][tx] = in[(size_t)(r0 + ty + j) * C + c0 + tx];
  __syncthreads();
  #pragma unroll
  for (int j = 0; j < 32; j += 8)
    out[(size_t)(c0 + ty + j) * R + r0 + tx] = f2b(tile[tx][ty + j]);
}

// ---------------- fused QKV + adapter-fc1 GEMM (v3: counted-vmcnt pipe) -----
// Round-3 post-mortem: per-K-step time ~1760cy vs ~250cy compute — the
// vmcnt(0) drain in __syncthreads dominates (T4 violated). v3:
//  - BK=64, dbuf, each K-half its own contiguous 8KB sub-buffer
//    lds[d][kh][128][32] so GLD16's linear dest works per half.
//  - per phase: stage next-step half (4 GLD16) -> frags -> 16 MFMA ->
//    s_waitcnt vmcnt(4) + raw s_barrier. 16KB always in flight; only the
//    last step drains. Induction: at each wait the 4 outstanding loads are
//    exactly the NEXT phase's half; WAR separated by >=1 barrier.
//  - T2 swizzle: chunk ^= (row&3)^((row>>2)&3), inverse applied on the
//    GLD16 global source; read XOR is lane-constant. 8-way -> uniform
//    2-way bank conflict (free).
__global__ __launch_bounds__(256, 4)
void gemm_qkv(const u16* __restrict__ X, const u16* __restrict__ Wt,
              const float* __restrict__ bq, const float* __restrict__ bk,
              const float* __restrict__ bv,
              const float* __restrict__ f1b, const float* __restrict__ efc1,
              const int* __restrict__ tptr,
              u16* __restrict__ qb, u16* __restrict__ kb, u16* __restrict__ vt,
              u16* __restrict__ hb)
{
  constexpr int K = 1024;
  __shared__ __align__(16) u16 ldsX[2][2][128 * 32];   // [dbuf][khalf][row][k]
  __shared__ __align__(16) u16 ldsW[2][2][128 * 32];
  const int tid = threadIdx.x;
  const int w = tid >> 6, lane = tid & 63, quad = lane >> 4, ln = lane & 15;
  // chunked XCD swizzle (bijective: 1600 % 8 == 0); within an XCD: 8 m-panels
  // (2MB of X, L2-resident) x all 25 n-panels.
  const int id = blockIdx.x;
  const int swzb = (id & 7) * 200 + (id >> 3);
  const int m0 = (swzb / 25) * 128;
  const int n0 = (swzb % 25) * 128;
  const int wrow = (w >> 1) * 64;
  const int wcol = (w & 1) * 64;

  // staging: thread t covers row trow (+64 for 2nd load), 16B chunk (t&3),
  // which must hold global chunk cg = (t&3)^((t>>2)&3)^((t>>4)&3)  (inverse swizzle)
  const int trow = tid >> 2;
  const int cgo  = (((tid & 3) ^ ((tid >> 2) & 3) ^ ((tid >> 4) & 3)) * 8);
  const u16* Xs = X  + (size_t)(m0 + trow) * K + cgo;
  const u16* Ws = Wt + (size_t)(n0 + trow) * K + cgo;

  #define STAGE(d, kt, kh) do { \
    GLD16(Xs + (size_t)(kt) * 64 + (kh) * 32,                  &ldsX[d][kh][w * 512]); \
    GLD16(Xs + (size_t)64 * K + (size_t)(kt) * 64 + (kh) * 32, &ldsX[d][kh][2048 + w * 512]); \
    GLD16(Ws + (size_t)(kt) * 64 + (kh) * 32,                  &ldsW[d][kh][w * 512]); \
    GLD16(Ws + (size_t)64 * K + (size_t)(kt) * 64 + (kh) * 32, &ldsW[d][kh][2048 + w * 512]); \
  } while (0)

  // read-side swizzled chunk offset (lane-constant: row&3 == ln&3,
  // (row>>2)&3 == (ln>>2)&3 for all frag rows)
  const int cA = (quad ^ (ln & 3) ^ ((ln >> 2) & 3)) * 8;

  f32x4 acc[4][4] = {};

  // prologue: both halves of K-tile 0; wait for half 0 (4 loads in flight)
  STAGE(0, 0, 0);
  STAGE(0, 0, 1);
  VMB(4);

  for (int kt = 0; kt < 16; ++kt) {
    const int d = kt & 1;
    #pragma unroll
    for (int kh = 0; kh < 2; ++kh) {
      if (kt + 1 < 16) STAGE(d ^ 1, kt + 1, kh);
      bf16x8 a[4], bfr[4];
      #pragma unroll
      for (int mt = 0; mt < 4; ++mt)
        a[mt] = *reinterpret_cast<const bf16x8*>(
            &ldsX[d][kh][(wrow + mt * 16 + ln) * 32 + cA]);
      #pragma unroll
      for (int nt = 0; nt < 4; ++nt)
        bfr[nt] = *reinterpret_cast<const bf16x8*>(
            &ldsW[d][kh][(wcol + nt * 16 + ln) * 32 + cA]);
      __builtin_amdgcn_s_setprio(1);
      #pragma unroll
      for (int mt = 0; mt < 4; ++mt)
        #pragma unroll
        for (int nt = 0; nt < 4; ++nt)
          acc[mt][nt] = mfma32(a[mt], bfr[nt], acc[mt][nt]);
      __builtin_amdgcn_s_setprio(0);
      if (kt + 1 < 16)      VMB(4);   // next phase's half landed; 4 in flight
      else if (kh == 0)     VMB(0);   // last tile: drain for final half
      // (kt==15, kh==1: no wait; epilogue touches no LDS)
    }
  }
  #undef STAGE

  if (n0 < 2048) {
    // Q scaled by 0.125*log2(e) so attn can use raw exp2.
    const float scale = (n0 < 1024) ? 0.18033688f : 1.f;
    const float* bias = (n0 < 1024) ? bq : bk;
    u16* dst = (n0 < 1024) ? qb : kb;
    const int nb = n0 & 1023;
    #pragma unroll
    for (int nt = 0; nt < 4; ++nt) {
      const int col = nb + wcol + nt * 16 + ln;
      const float bvv = bias[col];
      #pragma unroll
      for (int mt = 0; mt < 4; ++mt)
        #pragma unroll
        for (int r = 0; r < 4; ++r) {
          int row = m0 + wrow + mt * 16 + quad * 4 + r;
          dst[(size_t)row * 1024 + col] = f2b((acc[mt][nt][r] + bvv) * scale);
        }
    }
  } else if (n0 < 3072) {
    #pragma unroll
    for (int nt = 0; nt < 4; ++nt) {
      const int colv = (n0 - 2048) + wcol + nt * 16 + ln;
      const float bvv = bv[colv];
      const int h = colv >> 6, d2 = colv & 63;
      #pragma unroll
      for (int mt = 0; mt < 4; ++mt) {
        int row = m0 + wrow + mt * 16 + quad * 4;
        int bb = row >> 11, s = row & 2047;
        ushort4 o;
        o.x = f2b(acc[mt][nt][0] + bvv);
        o.y = f2b(acc[mt][nt][1] + bvv);
        o.z = f2b(acc[mt][nt][2] + bvv);
        o.w = f2b(acc[mt][nt][3] + bvv);
        *reinterpret_cast<ushort4*>(
            &vt[((((size_t)bb * NH + h) * DHD + d2) << 11) + s]) = o;
      }
    }
  } else if (wcol == 0) {
    // adapter fc1 tile: hb = relu(acc + b) * sigmoid(100*efc1[t]); cols 0..63
    int t = tptr[0];
    if ((unsigned)t > 9u) t = 0;
    #pragma unroll
    for (int nt = 0; nt < 4; ++nt) {
      const int col = nt * 16 + ln;
      const float bvv = f1b[col];
      const float g = 1.f / (1.f + __expf(-100.f * efc1[t * 64 + col]));
      #pragma unroll
      for (int mt = 0; mt < 4; ++mt)
        #pragma unroll
        for (int r = 0; r < 4; ++r) {
          int row = m0 + wrow + mt * 16 + quad * 4 + r;
          hb[(size_t)row * 64 + col] = f2b(fmaxf(acc[mt][nt][r] + bvv, 0.f) * g);
        }
    }
  }
}

// ---------------- flash attention + fused adapter fc2 -----------------------
// Round-2 variant restored (benched <=104.6 µs; round-3 revert was a mistake).
// grid (H, B, S/128): same-(b,h) blocks land on one XCD (L2-resident K/V);
// 4 blocks/CU — do NOT raise occupancy (round-1: L2 thrash, 13x HBM).
// Transposed-S: S^T = K·Q^T; P^T in regs is the B-operand of 16x16x16 PV.
// P->bf16 via scalar casts (v_cvt_pk_bf16_f32). Softmax denominator via
// mfma16(ones, P): every output row is the column-sum -> no VALU adds/shfl.
__global__ __launch_bounds__(256, 4)
void attn(const u16* __restrict__ Q, const u16* __restrict__ Kb,
          const u16* __restrict__ Vt, const u16* __restrict__ hb,
          const u16* __restrict__ w2, const float* __restrict__ b2,
          const float* __restrict__ gate2, const int* __restrict__ tptr,
          float* __restrict__ out)
{
  __shared__ __align__(16) u16 ldsK[64 * 72];     // [key][d]  stride 72 (b128 floor)
  __shared__ __align__(16) u16 ldsV[64 * 76];     // [d][key]  stride 76 (b64 floor)

  const int tid = threadIdx.x;
  const int w = tid >> 6, lane = tid & 63, quad = lane >> 4, ln = lane & 15;
  const int h = blockIdx.x, b = blockIdx.y, qt = blockIdx.z;
  const int bh = b * NH + h;
  const int qbase = qt * 128 + w * 32;
  const int skey = tid >> 3;
  const int sd   = (tid & 7) * 8;

  bf16x8 qf[2][2];
  #pragma unroll
  for (int q2 = 0; q2 < 2; ++q2)
    #pragma unroll
    for (int kk = 0; kk < 2; ++kk)
      qf[q2][kk] = *reinterpret_cast<const bf16x8*>(
          &Q[(size_t)(b * SS + qbase + q2 * 16 + ln) * HIDD + h * DHD + kk * 32 + quad * 8]);

  f32x4 o[4][2] = {};          // O^T[d=dt*16+quad*4+r][q=q2*16+ln]
  f32x4 lacc[2] = {};          // denom: every row of ones^T·P^T = colsum
  const s16x4 ones = {0x3F80, 0x3F80, 0x3F80, 0x3F80};   // bf16 1.0 x4

  const u16* Kp = &Kb[(size_t)(b * SS + skey) * HIDD + h * DHD + sd];
  const u16* Vp = &Vt[((size_t)bh * DHD + skey) * SS + sd];

  uint4 rK0 = *reinterpret_cast<const uint4*>(Kp);
  uint4 rK1 = *reinterpret_cast<const uint4*>(Kp + (size_t)32 * HIDD);
  uint4 rV0 = *reinterpret_cast<const uint4*>(Vp);
  uint4 rV1 = *reinterpret_cast<const uint4*>(Vp + (size_t)32 * SS);

  for (int kt = 0; kt < SS; kt += 64) {
    LDS_BARRIER();
    *reinterpret_cast<uint4*>(&ldsK[skey * 72 + sd])        = rK0;
    *reinterpret_cast<uint4*>(&ldsK[(32 + skey) * 72 + sd]) = rK1;
    *reinterpret_cast<uint4*>(&ldsV[skey * 76 + sd])        = rV0;
    *reinterpret_cast<uint4*>(&ldsV[(32 + skey) * 76 + sd]) = rV1;
    if (kt + 64 < SS) {
      const u16* Kn = Kp + (size_t)(kt + 64) * HIDD;
      const u16* Vn = Vp + (kt + 64);
      rK0 = *reinterpret_cast<const uint4*>(Kn);
      rK1 = *reinterpret_cast<const uint4*>(Kn + (size_t)32 * HIDD);
      rV0 = *reinterpret_cast<const uint4*>(Vn);
      rV1 = *reinterpret_cast<const uint4*>(Vn + (size_t)32 * SS);
    }
    LDS_BARRIER();

    // S^T = K Q^T
    f32x4 s[4][2];
    __builtin_amdgcn_s_setprio(1);
    #pragma unroll
    for (int k4 = 0; k4 < 4; ++k4) {
      bf16x8 kf0 = *reinterpret_cast<const bf16x8*>(&ldsK[(k4 * 16 + ln) * 72 + quad * 8]);
      bf16x8 kf1 = *reinterpret_cast<const bf16x8*>(&ldsK[(k4 * 16 + ln) * 72 + 32 + quad * 8]);
      #pragma unroll
      for (int q2 = 0; q2 < 2; ++q2) {
        f32x4 z = {0.f, 0.f, 0.f, 0.f};
        z = mfma32(kf0, qf[q2][0], z);
        z = mfma32(kf1, qf[q2][1], z);
        s[k4][q2] = z;
      }
    }
    __builtin_amdgcn_s_setprio(0);

    // P^T = 2^(S^T) (Q pre-scaled by log2e/8); stays in registers
    s16x4 p[4][2];
    #pragma unroll
    for (int k4 = 0; k4 < 4; ++k4)
      #pragma unroll
      for (int q2 = 0; q2 < 2; ++q2) {
        union { bf16x4 b; s16x4 s; } cv;
        #pragma unroll
        for (int r = 0; r < 4; ++r)
          cv.b[r] = (__bf16)EXP2(s[k4][q2][r]);   // v_cvt_pk_bf16_f32 path
        p[k4][q2] = cv.s;
      }

    // O^T += V^T P^T ;  denom += ones^T P^T (MFMA does the key-reduction)
    __builtin_amdgcn_s_setprio(1);
    #pragma unroll
    for (int dt = 0; dt < 4; ++dt) {
      #pragma unroll
      for (int ks = 0; ks < 4; ++ks) {
        s16x4 vf = *reinterpret_cast<const s16x4*>(
            &ldsV[(dt * 16 + ln) * 76 + ks * 16 + quad * 4]);
        #pragma unroll
        for (int q2 = 0; q2 < 2; ++q2)
          o[dt][q2] = mfma16(vf, p[ks][q2], o[dt][q2]);
      }
    }
    #pragma unroll
    for (int ks = 0; ks < 4; ++ks)
      #pragma unroll
      for (int q2 = 0; q2 < 2; ++q2)
        lacc[q2] = mfma16(ones, p[ks][q2], lacc[q2]);
    __builtin_amdgcn_s_setprio(0);
  }

  // softmax denominators: lacc rows all equal the column sum for q=ln
  float rl[2];
  #pragma unroll
  for (int q2 = 0; q2 < 2; ++q2)
    rl[q2] = 1.f / lacc[q2][0];

  // fused adapter fc2 tile: acc2 in O^T layout (A=wtf2 rows=d, B=hb rows=q)
  f32x4 acc2[4][2] = {};
  #pragma unroll
  for (int kk = 0; kk < 2; ++kk) {
    bf16x8 hf[2];
    #pragma unroll
    for (int q2 = 0; q2 < 2; ++q2) {
      int q = qbase + q2 * 16 + ln;
      hf[q2] = *reinterpret_cast<const bf16x8*>(
          &hb[(size_t)(b * SS + q) * 64 + kk * 32 + quad * 8]);
    }
    #pragma unroll
    for (int dt = 0; dt < 4; ++dt) {
      bf16x8 wf = *reinterpret_cast<const bf16x8*>(
          &w2[(size_t)(h * DHD + dt * 16 + ln) * 64 + kk * 32 + quad * 8]);
      #pragma unroll
      for (int q2 = 0; q2 < 2; ++q2)
        acc2[dt][q2] = mfma32(wf, hf[q2], acc2[dt][q2]);
    }
  }

  int t = tptr[0];
  if ((unsigned)t > 9u) t = 0;
  float bv2[4][4], gv2[4][4];
  #pragma unroll
  for (int dt = 0; dt < 4; ++dt)
    #pragma unroll
    for (int r = 0; r < 4; ++r) {
      int col = h * DHD + dt * 16 + quad * 4 + r;
      bv2[dt][r] = b2[col];
      gv2[dt][r] = 1.f / (1.f + __expf(-100.f * gate2[t * HIDD + col]));
    }

  #pragma unroll
  for (int q2 = 0; q2 < 2; ++q2) {
    const int q = qbase + q2 * 16 + ln;
    float* orow = &out[(size_t)(b * SS + q) * HIDD + h * DHD];
    #pragma unroll
    for (int dt = 0; dt < 4; ++dt)
      #pragma unroll
      for (int r = 0; r < 4; ++r) {
        int d = dt * 16 + quad * 4 + r;
        float ad = fmaxf(acc2[dt][q2][r] + bv2[dt][r], 0.f) * gv2[dt][r];
        orow[d] = o[dt][q2][r] * rl[q2] + ad;
      }
  }
}

// ---------------------------------------------------------------------------
extern "C" void kernel_launch(void* const* d_in, const int* in_sizes, int n_in,
                              void* d_out, int out_size, void* d_ws, size_t ws_size,
                              hipStream_t stream) {
  const float* x    = (const float*)d_in[0];
  const float* Wq   = (const float*)d_in[1];
  const float* bq   = (const float*)d_in[2];
  const float* Wk   = (const float*)d_in[3];
  const float* bk   = (const float*)d_in[4];
  const float* Wv   = (const float*)d_in[5];
  const float* bv   = (const float*)d_in[6];
  const float* f1w  = (const float*)d_in[7];
  const float* f1b  = (const float*)d_in[8];
  const float* f2w  = (const float*)d_in[9];
  const float* f2b_ = (const float*)d_in[10];
  const float* efc1 = (const float*)d_in[11];
  const float* efc2 = (const float*)d_in[12];
  const int*   tptr = (const int*)d_in[13];
  float* out = (float*)d_out;

  unsigned char* ws = (unsigned char*)d_ws;
  u16* xb   = (u16*)(ws + 0);                            // 16 MB   [8192][1024]
  u16* wqkv = (u16*)(ws + (16u << 20));                  // 6.25 MB [3200][1024]
  u16* wtf1 = wqkv + (size_t)3072 * 1024;                // rows 3072..3135 of wqkv
  u16* wtf2 = (u16*)(ws + (22u << 20) + (256u << 10));   // 128 KB  [1024][64]
  u16* hb   = (u16*)(ws + (23u << 20));                  // 1 MB    [8192][64]
  u16* qb   = (u16*)(ws + (24u << 20));                  // 16 MB   [8192][1024]
  u16* kb   = (u16*)(ws + (40u << 20));                  // 16 MB
  u16* vt   = (u16*)(ws + (56u << 20));                  // 16 MB   [64][64][2048]

  prep<<<dim3(11424), 256, 0, stream>>>(x, xb, Wq, Wk, Wv, f1w, f2w,
                                        wqkv, wtf1, wtf2);

  gemm_qkv<<<dim3(1600), 256, 0, stream>>>(xb, wqkv, bq, bk, bv,
                                           f1b, efc1, tptr, qb, kb, vt, hb);

  attn<<<dim3(NH, BB, SS / 128), 256, 0, stream>>>(
      qb, kb, vt, hb, wtf2, f2b_, efc2, tptr, out);
}

// Round 5
// 273.855 us; speedup vs baseline: 1.0966x; 1.0966x over previous
//
#include <hip/hip_runtime.h>
#include <stdint.h>
#include <stddef.h>

typedef unsigned short u16;
typedef unsigned int u32;
typedef __bf16 bf16x8 __attribute__((ext_vector_type(8)));
typedef __bf16 bf16x4 __attribute__((ext_vector_type(4)));
typedef short s16x4 __attribute__((ext_vector_type(4)));
typedef float f32x4 __attribute__((ext_vector_type(4)));

#define BB  4
#define SS  2048
#define HIDD 1024
#define NH  16
#define DHD 64

// async global->LDS, 16B per lane. LDS dest = WAVE-UNIFORM base; HW adds lane*16.
#define GLD16(gaddr, laddr) \
  __builtin_amdgcn_global_load_lds( \
      (const __attribute__((address_space(1))) u32*)(gaddr), \
      (__attribute__((address_space(3))) u32*)(laddr), 16, 0, 0)

// barrier that waits ONLY on LDS ops (no vmcnt drain — keeps prefetch in flight)
#define LDS_BARRIER() asm volatile("s_waitcnt lgkmcnt(0)\n\ts_barrier" ::: "memory")

// counted-vmcnt barrier: wait until only N vmem ops outstanding, then barrier.
#define VMB(n) asm volatile("s_waitcnt vmcnt(" #n ")\n\ts_barrier" ::: "memory")

// 2^x. Q is pre-scaled by 0.125*log2(e), so exp(s/8) == EXP2(s').
#if __has_builtin(__builtin_amdgcn_exp2f)
  #define EXP2(x) __builtin_amdgcn_exp2f(x)
#else
  #define EXP2(x) __expf((x) * 0.6931471805599453f)
#endif

__device__ __forceinline__ u16 f2b(float f){
  union { float f; unsigned u; } c; c.f = f;
  unsigned r = c.u + 0x7fffu + ((c.u >> 16) & 1u);
  return (u16)(r >> 16);
}
__device__ __forceinline__ f32x4 mfma32(bf16x8 a, bf16x8 b, f32x4 c){
  return __builtin_amdgcn_mfma_f32_16x16x32_bf16(a, b, c, 0, 0, 0);
}
__device__ __forceinline__ f32x4 mfma16(s16x4 a, s16x4 b, f32x4 c){
  return __builtin_amdgcn_mfma_f32_16x16x16bf16_1k(a, b, c, 0, 0, 0);
}

// ---------------- fused prologue: cvt + all weight transposes ---------------
// blocks: [0,8192) x->bf16 cvt; [8192,11264) Wq/Wk/Wv transpose;
// [11264,11328) fc1_w transpose (lands at wqkv rows 3072..3135);
// [11328,11392) fc2_w transpose; [11392,11488) zero-pad wqkv rows 3136..3327
// (N padded to 3328 = 13 tiles of 256 for the 256-wide GEMM).
__global__ __launch_bounds__(256)
void prep(const float* __restrict__ x, u16* __restrict__ xb,
          const float* __restrict__ Wq, const float* __restrict__ Wk,
          const float* __restrict__ Wv, const float* __restrict__ f1w,
          const float* __restrict__ f2w,
          u16* __restrict__ wqkv, u16* __restrict__ wtf1, u16* __restrict__ wtf2)
{
  __shared__ float tile[32][33];
  int blk = blockIdx.x;
  const int tid = threadIdx.x;
  if (blk < 8192) {
    int i = blk * 1024 + tid * 4;
    float4 v = *reinterpret_cast<const float4*>(&x[i]);
    ushort4 o;
    o.x = f2b(v.x); o.y = f2b(v.y); o.z = f2b(v.z); o.w = f2b(v.w);
    *reinterpret_cast<ushort4*>(&xb[i]) = o;
    return;
  }
  blk -= 8192;
  if (blk >= 3200) {                       // zero-pad rows 3136..3327 of wqkv
    u16* pad = wqkv + (size_t)3136 * 1024;
    uint4 z = make_uint4(0u, 0u, 0u, 0u);
    *reinterpret_cast<uint4*>(&pad[(size_t)(blk - 3200) * 2048 + tid * 8]) = z;
    return;
  }
  const float* in; u16* out; int R, C, c0, r0;
  if (blk < 3072) {
    int m = blk >> 10, t = blk & 1023;
    in = (m == 0) ? Wq : (m == 1) ? Wk : Wv;
    out = wqkv + (size_t)m * 1024 * 1024;
    R = 1024; C = 1024; c0 = (t & 31) * 32; r0 = (t >> 5) * 32;
  } else if (blk < 3136) {
    int t = blk - 3072;
    in = f1w; out = wtf1; R = 1024; C = 64;
    c0 = (t & 1) * 32; r0 = (t >> 1) * 32;
  } else {
    int t = blk - 3136;
    in = f2w; out = wtf2; R = 64; C = 1024;
    c0 = (t & 31) * 32; r0 = (t >> 5) * 32;
  }
  int tx = tid & 31, ty = tid >> 5;
  #pragma unroll
  for (int j = 0; j < 32; j += 8)
    tile[ty + j][tx] = in[(size_t)(r0 + ty + j) * C + c0 + tx];
  __syncthreads();
  #pragma unroll
  for (int j = 0; j < 32; j += 8)
    out[(size_t)(c0 + ty + j) * R + r0 + tx] = f2b(tile[tx][ty + j]);
}

// ---------------- fused QKV + adapter-fc1 GEMM (v4: fat wave tile) ----------
// Round-4 post-mortem: 3 staging schedules (single-buf drain / dbuf drain /
// counted-vmcnt) all ~106 µs -> staging latency is NOT the limiter; the
// per-phase LDS-read/issue path at fixed 8 waves/CU is. v4 changes GEOMETRY:
//  - wave tile 64x128 (MT=4, NT=8): 12 ds_read_b128 per 32 MFMA (was 8:16)
//    -> 25% less LDS-read per FLOP. Block 128x256, 4 waves, 832 blocks.
//  - 3-buffer LDS ring (24KB each, 72KB total, 2 blocks/CU): with 3 bufs the
//    vmcnt(6) wait keeps a FULL tile (t+2) in flight across the barrier —
//    with 2 bufs that was impossible (the wait had to drain).
//  - Wt padded to 3328 rows = 13 N-tiles of 256; tile 12 = fc1 (cols 0..63).
//  - no setprio (m190: negative on barrier-lockstep GEMM).
__global__ __launch_bounds__(256, 2)
void gemm_qkv(const u16* __restrict__ X, const u16* __restrict__ Wt,
              const float* __restrict__ bq, const float* __restrict__ bk,
              const float* __restrict__ bv,
              const float* __restrict__ f1b, const float* __restrict__ efc1,
              const int* __restrict__ tptr,
              u16* __restrict__ qb, u16* __restrict__ kb, u16* __restrict__ vt,
              u16* __restrict__ hb)
{
  constexpr int K = 1024;
  __shared__ __align__(16) u16 ldsA[3][128 * 32];   // 3 x 8KB
  __shared__ __align__(16) u16 ldsB[3][256 * 32];   // 3 x 16KB
  const int tid = threadIdx.x;
  const int w = tid >> 6, lane = tid & 63, quad = lane >> 4, ln = lane & 15;
  // chunked XCD swizzle (bijective: 832 % 8 == 0): XCD owns 8 contiguous
  // m-panels (2MB X, L2-resident) x all 13 n-panels.
  const int id = blockIdx.x;
  const int swz = (id & 7) * 104 + (id >> 3);
  const int m0 = (swz / 13) * 128;
  const int n0 = (swz % 13) * 256;
  const int wrow = (w >> 1) * 64;          // wave M-offset (2 wave-rows)
  const int wcol = (w & 1) * 128;          // wave N-offset (2 wave-cols)

  // staging source base for this thread (GLD16 dest is wave-uniform; HW
  // spreads lanes as +lane*16B => lane covers row +lane/4, chunk lane&3)
  const u16* Xs = X  + (size_t)(m0 + w * 32 + (lane >> 2)) * K + (lane & 3) * 8;
  const u16* Ws = Wt + (size_t)(n0 + w * 64 + (lane >> 2)) * K + (lane & 3) * 8;

  // per K-step per wave: 2 GLD16 for A (wave covers 32 rows) + 4 for B (64
  // rows) = 6 outstanding per staged tile -> VMB(6) leaves one tile in flight.
  #define STAGE(buf, kk) do { \
    GLD16(Xs + (size_t)(kk),            &ldsA[buf][w * 1024]); \
    GLD16(Xs + (size_t)16 * K + (kk),   &ldsA[buf][w * 1024 + 512]); \
    GLD16(Ws + (size_t)(kk),            &ldsB[buf][w * 2048]); \
    GLD16(Ws + (size_t)16 * K + (kk),   &ldsB[buf][w * 2048 + 512]); \
    GLD16(Ws + (size_t)32 * K + (kk),   &ldsB[buf][w * 2048 + 1024]); \
    GLD16(Ws + (size_t)48 * K + (kk),   &ldsB[buf][w * 2048 + 1536]); \
  } while (0)

  f32x4 acc[4][8] = {};

  // prologue: stage tiles 0,1 into bufs 0,1; wait tile 0 (6 left in flight)
  STAGE(0, 0);
  STAGE(1, 32);
  VMB(6);

  int cur = 0;
  for (int t = 0; t < 32; ++t) {
    if (t + 2 < 32) {
      int sb = cur + 2; if (sb >= 3) sb -= 3;
      STAGE(sb, (t + 2) * 32);            // 12 in flight after this
    }

    bf16x8 a[4], b[8];
    #pragma unroll
    for (int mt = 0; mt < 4; ++mt)
      a[mt] = *reinterpret_cast<const bf16x8*>(
          &ldsA[cur][(wrow + mt * 16 + ln) * 32 + quad * 8]);
    #pragma unroll
    for (int nt = 0; nt < 8; ++nt)
      b[nt] = *reinterpret_cast<const bf16x8*>(
          &ldsB[cur][(wcol + nt * 16 + ln) * 32 + quad * 8]);
    #pragma unroll
    for (int mt = 0; mt < 4; ++mt)
      #pragma unroll
      for (int nt = 0; nt < 8; ++nt)
        acc[mt][nt] = mfma32(a[mt], b[nt], acc[mt][nt]);

    if (t + 2 < 32)      VMB(6);   // tile t+1 landed; tile t+2 stays in flight
    else if (t == 30)    VMB(0);   // drain tile 31 before final compute
    // t == 31: no wait; epilogue touches no LDS

    cur = (cur + 1 == 3) ? 0 : cur + 1;
  }
  #undef STAGE

  if (n0 < 2048) {
    // Q scaled by 0.125*log2(e) so attn can use raw exp2.
    const float scale = (n0 < 1024) ? 0.18033688f : 1.f;
    const float* bias = (n0 < 1024) ? bq : bk;
    u16* dst = (n0 < 1024) ? qb : kb;
    const int nb = n0 & 1023;
    #pragma unroll
    for (int nt = 0; nt < 8; ++nt) {
      const int col = nb + wcol + nt * 16 + ln;
      const float bvv = bias[col];
      #pragma unroll
      for (int mt = 0; mt < 4; ++mt)
        #pragma unroll
        for (int r = 0; r < 4; ++r) {
          int row = m0 + wrow + mt * 16 + quad * 4 + r;
          dst[(size_t)row * 1024 + col] = f2b((acc[mt][nt][r] + bvv) * scale);
        }
    }
  } else if (n0 < 3072) {
    #pragma unroll
    for (int nt = 0; nt < 8; ++nt) {
      const int colv = (n0 - 2048) + wcol + nt * 16 + ln;
      const float bvv = bv[colv];
      const int h = colv >> 6, d2 = colv & 63;
      #pragma unroll
      for (int mt = 0; mt < 4; ++mt) {
        int row = m0 + wrow + mt * 16 + quad * 4;
        int bb = row >> 11, s = row & 2047;
        ushort4 o;
        o.x = f2b(acc[mt][nt][0] + bvv);
        o.y = f2b(acc[mt][nt][1] + bvv);
        o.z = f2b(acc[mt][nt][2] + bvv);
        o.w = f2b(acc[mt][nt][3] + bvv);
        *reinterpret_cast<ushort4*>(
            &vt[((((size_t)bb * NH + h) * DHD + d2) << 11) + s]) = o;
      }
    }
  } else if ((w & 1) == 0) {
    // adapter fc1 tile (n0==3072): valid cols 0..63 = first 4 nt of wcol==0
    int t = tptr[0];
    if ((unsigned)t > 9u) t = 0;
    #pragma unroll
    for (int nt = 0; nt < 4; ++nt) {
      const int col = nt * 16 + ln;
      const float bvv = f1b[col];
      const float g = 1.f / (1.f + __expf(-100.f * efc1[t * 64 + col]));
      #pragma unroll
      for (int mt = 0; mt < 4; ++mt)
        #pragma unroll
        for (int r = 0; r < 4; ++r) {
          int row = m0 + wrow + mt * 16 + quad * 4 + r;
          hb[(size_t)row * 64 + col] = f2b(fmaxf(acc[mt][nt][r] + bvv, 0.f) * g);
        }
    }
  }
}

// ---------------- flash attention + fused adapter fc2 -----------------------
// Measured <=104.6 µs (round-2). grid (H, B, S/128): same-(b,h) blocks land
// on one XCD (L2-resident K/V); 4 blocks/CU — do NOT raise occupancy
// (round-1: L2 thrash, 13x HBM). Transposed-S: S^T = K·Q^T; P^T in regs is
// the B-operand of 16x16x16 PV. Softmax denominator via mfma16(ones, P).
__global__ __launch_bounds__(256, 4)
void attn(const u16* __restrict__ Q, const u16* __restrict__ Kb,
          const u16* __restrict__ Vt, const u16* __restrict__ hb,
          const u16* __restrict__ w2, const float* __restrict__ b2,
          const float* __restrict__ gate2, const int* __restrict__ tptr,
          float* __restrict__ out)
{
  __shared__ __align__(16) u16 ldsK[64 * 72];     // [key][d]  stride 72 (b128 floor)
  __shared__ __align__(16) u16 ldsV[64 * 76];     // [d][key]  stride 76 (b64 floor)

  const int tid = threadIdx.x;
  const int w = tid >> 6, lane = tid & 63, quad = lane >> 4, ln = lane & 15;
  const int h = blockIdx.x, b = blockIdx.y, qt = blockIdx.z;
  const int bh = b * NH + h;
  const int qbase = qt * 128 + w * 32;
  const int skey = tid >> 3;
  const int sd   = (tid & 7) * 8;

  bf16x8 qf[2][2];
  #pragma unroll
  for (int q2 = 0; q2 < 2; ++q2)
    #pragma unroll
    for (int kk = 0; kk < 2; ++kk)
      qf[q2][kk] = *reinterpret_cast<const bf16x8*>(
          &Q[(size_t)(b * SS + qbase + q2 * 16 + ln) * HIDD + h * DHD + kk * 32 + quad * 8]);

  f32x4 o[4][2] = {};          // O^T[d=dt*16+quad*4+r][q=q2*16+ln]
  f32x4 lacc[2] = {};          // denom: every row of ones^T·P^T = colsum
  const s16x4 ones = {0x3F80, 0x3F80, 0x3F80, 0x3F80};   // bf16 1.0 x4

  const u16* Kp = &Kb[(size_t)(b * SS + skey) * HIDD + h * DHD + sd];
  const u16* Vp = &Vt[((size_t)bh * DHD + skey) * SS + sd];

  uint4 rK0 = *reinterpret_cast<const uint4*>(Kp);
  uint4 rK1 = *reinterpret_cast<const uint4*>(Kp + (size_t)32 * HIDD);
  uint4 rV0 = *reinterpret_cast<const uint4*>(Vp);
  uint4 rV1 = *reinterpret_cast<const uint4*>(Vp + (size_t)32 * SS);

  for (int kt = 0; kt < SS; kt += 64) {
    LDS_BARRIER();
    *reinterpret_cast<uint4*>(&ldsK[skey * 72 + sd])        = rK0;
    *reinterpret_cast<uint4*>(&ldsK[(32 + skey) * 72 + sd]) = rK1;
    *reinterpret_cast<uint4*>(&ldsV[skey * 76 + sd])        = rV0;
    *reinterpret_cast<uint4*>(&ldsV[(32 + skey) * 76 + sd]) = rV1;
    if (kt + 64 < SS) {
      const u16* Kn = Kp + (size_t)(kt + 64) * HIDD;
      const u16* Vn = Vp + (kt + 64);
      rK0 = *reinterpret_cast<const uint4*>(Kn);
      rK1 = *reinterpret_cast<const uint4*>(Kn + (size_t)32 * HIDD);
      rV0 = *reinterpret_cast<const uint4*>(Vn);
      rV1 = *reinterpret_cast<const uint4*>(Vn + (size_t)32 * SS);
    }
    LDS_BARRIER();

    // S^T = K Q^T
    f32x4 s[4][2];
    __builtin_amdgcn_s_setprio(1);
    #pragma unroll
    for (int k4 = 0; k4 < 4; ++k4) {
      bf16x8 kf0 = *reinterpret_cast<const bf16x8*>(&ldsK[(k4 * 16 + ln) * 72 + quad * 8]);
      bf16x8 kf1 = *reinterpret_cast<const bf16x8*>(&ldsK[(k4 * 16 + ln) * 72 + 32 + quad * 8]);
      #pragma unroll
      for (int q2 = 0; q2 < 2; ++q2) {
        f32x4 z = {0.f, 0.f, 0.f, 0.f};
        z = mfma32(kf0, qf[q2][0], z);
        z = mfma32(kf1, qf[q2][1], z);
        s[k4][q2] = z;
      }
    }
    __builtin_amdgcn_s_setprio(0);

    // P^T = 2^(S^T) (Q pre-scaled by log2e/8); stays in registers
    s16x4 p[4][2];
    #pragma unroll
    for (int k4 = 0; k4 < 4; ++k4)
      #pragma unroll
      for (int q2 = 0; q2 < 2; ++q2) {
        union { bf16x4 b; s16x4 s; } cv;
        #pragma unroll
        for (int r = 0; r < 4; ++r)
          cv.b[r] = (__bf16)EXP2(s[k4][q2][r]);   // v_cvt_pk_bf16_f32 path
        p[k4][q2] = cv.s;
      }

    // O^T += V^T P^T ;  denom += ones^T P^T (MFMA does the key-reduction)
    __builtin_amdgcn_s_setprio(1);
    #pragma unroll
    for (int dt = 0; dt < 4; ++dt) {
      #pragma unroll
      for (int ks = 0; ks < 4; ++ks) {
        s16x4 vf = *reinterpret_cast<const s16x4*>(
            &ldsV[(dt * 16 + ln) * 76 + ks * 16 + quad * 4]);
        #pragma unroll
        for (int q2 = 0; q2 < 2; ++q2)
          o[dt][q2] = mfma16(vf, p[ks][q2], o[dt][q2]);
      }
    }
    #pragma unroll
    for (int ks = 0; ks < 4; ++ks)
      #pragma unroll
      for (int q2 = 0; q2 < 2; ++q2)
        lacc[q2] = mfma16(ones, p[ks][q2], lacc[q2]);
    __builtin_amdgcn_s_setprio(0);
  }

  // softmax denominators: lacc rows all equal the column sum for q=ln
  float rl[2];
  #pragma unroll
  for (int q2 = 0; q2 < 2; ++q2)
    rl[q2] = 1.f / lacc[q2][0];

  // fused adapter fc2 tile: acc2 in O^T layout (A=wtf2 rows=d, B=hb rows=q)
  f32x4 acc2[4][2] = {};
  #pragma unroll
  for (int kk = 0; kk < 2; ++kk) {
    bf16x8 hf[2];
    #pragma unroll
    for (int q2 = 0; q2 < 2; ++q2) {
      int q = qbase + q2 * 16 + ln;
      hf[q2] = *reinterpret_cast<const bf16x8*>(
          &hb[(size_t)(b * SS + q) * 64 + kk * 32 + quad * 8]);
    }
    #pragma unroll
    for (int dt = 0; dt < 4; ++dt) {
      bf16x8 wf = *reinterpret_cast<const bf16x8*>(
          &w2[(size_t)(h * DHD + dt * 16 + ln) * 64 + kk * 32 + quad * 8]);
      #pragma unroll
      for (int q2 = 0; q2 < 2; ++q2)
        acc2[dt][q2] = mfma32(wf, hf[q2], acc2[dt][q2]);
    }
  }

  int t = tptr[0];
  if ((unsigned)t > 9u) t = 0;
  float bv2[4][4], gv2[4][4];
  #pragma unroll
  for (int dt = 0; dt < 4; ++dt)
    #pragma unroll
    for (int r = 0; r < 4; ++r) {
      int col = h * DHD + dt * 16 + quad * 4 + r;
      bv2[dt][r] = b2[col];
      gv2[dt][r] = 1.f / (1.f + __expf(-100.f * gate2[t * HIDD + col]));
    }

  #pragma unroll
  for (int q2 = 0; q2 < 2; ++q2) {
    const int q = qbase + q2 * 16 + ln;
    float* orow = &out[(size_t)(b * SS + q) * HIDD + h * DHD];
    #pragma unroll
    for (int dt = 0; dt < 4; ++dt)
      #pragma unroll
      for (int r = 0; r < 4; ++r) {
        int d = dt * 16 + quad * 4 + r;
        float ad = fmaxf(acc2[dt][q2][r] + bv2[dt][r], 0.f) * gv2[dt][r];
        orow[d] = o[dt][q2][r] * rl[q2] + ad;
      }
  }
}

// ---------------------------------------------------------------------------
extern "C" void kernel_launch(void* const* d_in, const int* in_sizes, int n_in,
                              void* d_out, int out_size, void* d_ws, size_t ws_size,
                              hipStream_t stream) {
  const float* x    = (const float*)d_in[0];
  const float* Wq   = (const float*)d_in[1];
  const float* bq   = (const float*)d_in[2];
  const float* Wk   = (const float*)d_in[3];
  const float* bk   = (const float*)d_in[4];
  const float* Wv   = (const float*)d_in[5];
  const float* bv   = (const float*)d_in[6];
  const float* f1w  = (const float*)d_in[7];
  const float* f1b  = (const float*)d_in[8];
  const float* f2w  = (const float*)d_in[9];
  const float* f2b_ = (const float*)d_in[10];
  const float* efc1 = (const float*)d_in[11];
  const float* efc2 = (const float*)d_in[12];
  const int*   tptr = (const int*)d_in[13];
  float* out = (float*)d_out;

  unsigned char* ws = (unsigned char*)d_ws;
  u16* xb   = (u16*)(ws + 0);                            // 16 MB  [8192][1024]
  u16* wqkv = (u16*)(ws + (16u << 20));                  // 6.5 MB [3328][1024]
  u16* wtf1 = wqkv + (size_t)3072 * 1024;                // rows 3072..3135 of wqkv
  u16* wtf2 = (u16*)(ws + (22u << 20) + (512u << 10));   // 128 KB [1024][64]
  u16* hb   = (u16*)(ws + (23u << 20));                  // 1 MB   [8192][64]
  u16* qb   = (u16*)(ws + (24u << 20));                  // 16 MB  [8192][1024]
  u16* kb   = (u16*)(ws + (40u << 20));                  // 16 MB
  u16* vt   = (u16*)(ws + (56u << 20));                  // 16 MB  [64][64][2048]

  prep<<<dim3(11488), 256, 0, stream>>>(x, xb, Wq, Wk, Wv, f1w, f2w,
                                        wqkv, wtf1, wtf2);

  gemm_qkv<<<dim3(832), 256, 0, stream>>>(xb, wqkv, bq, bk, bv,
                                          f1b, efc1, tptr, qb, kb, vt, hb);

  attn<<<dim3(NH, BB, SS / 128), 256, 0, stream>>>(
      qb, kb, vt, hb, wtf2, f2b_, efc2, tptr, out);
}